// Round 11
// baseline (1869.809 us; speedup 1.0000x reference)
//
#include <hip/hip_runtime.h>

#define T4096 4096
#define CH 64
typedef unsigned long long u64;

// ---------------------------------------------------------------------------
// QKV: O[b][s][c] = sum_t W[s][t] * X[b][c][t]   (NT gemm, both row-major in t)
// tile 128(s) x 64(c), K-step 64, 512 threads, 4x4 micro-tile.
// All three outputs token-major [b][s][c] (Q special layout dropped in R11).
// Per-output fmaf chain k-ascending over identical values -> bit-identical.
// ---------------------------------------------------------------------------
__global__ __launch_bounds__(512) void gemm_qkv(
    const float* __restrict__ X,
    const float* __restrict__ Wq, const float* __restrict__ Wk, const float* __restrict__ Wv,
    float* __restrict__ QT, float* __restrict__ KT, float* __restrict__ VT)
{
    const float* W = (blockIdx.z == 0) ? Wq : (blockIdx.z == 1) ? Wk : Wv;
    float*       O = (blockIdx.z == 0) ? QT : (blockIdx.z == 1) ? KT : VT;
    const int b  = blockIdx.y;
    const int s0 = blockIdx.x * 128;

    __shared__ float As[64][132];   // [k][m^swz]
    __shared__ float Bs[64][68];    // [k][c^swz]

    const int tid = threadIdx.x;
    const int tx = tid & 15;   const int c0 = tx * 4;
    const int my = tid >> 4;   const int m0 = my * 4;   // 0..124
    const int lr = tid >> 3;            // 0..63
    const int lk = (tid & 7) * 4;       // 0..28
    const int sw = lk;

    float acc[4][4];
#pragma unroll
    for (int i = 0; i < 4; ++i)
#pragma unroll
        for (int j = 0; j < 4; ++j) acc[i][j] = 0.f;

    const float* Xb = X + (size_t)b * CH * T4096;

    for (int k0 = 0; k0 < T4096; k0 += 64) {
#pragma unroll
        for (int kk = 0; kk < 2; ++kk) {
            const int kb = 32 * kk + lk;
#pragma unroll
            for (int p = 0; p < 2; ++p) {   // A: 128 rows
                int row = lr + 64 * p;
                float4 v = *(const float4*)(W + (size_t)(s0 + row) * T4096 + k0 + kb);
                int col = row ^ sw;
                As[kb + 0][col] = v.x; As[kb + 1][col] = v.y;
                As[kb + 2][col] = v.z; As[kb + 3][col] = v.w;
            }
            {   // B: 64 rows (channels)
                int row = lr;
                float4 v = *(const float4*)(Xb + (size_t)row * T4096 + k0 + kb);
                int col = row ^ sw;
                Bs[kb + 0][col] = v.x; Bs[kb + 1][col] = v.y;
                Bs[kb + 2][col] = v.z; Bs[kb + 3][col] = v.w;
            }
        }
        __syncthreads();
#pragma unroll
        for (int k = 0; k < 64; ++k) {
            const int swk = k & 28;
            float4 a  = *(const float4*)&As[k][m0 ^ swk];
            float4 bv = *(const float4*)&Bs[k][c0 ^ swk];
            float am[4] = {a.x, a.y, a.z, a.w};
            float bn[4] = {bv.x, bv.y, bv.z, bv.w};
#pragma unroll
            for (int i = 0; i < 4; ++i)
#pragma unroll
                for (int j = 0; j < 4; ++j) acc[i][j] = fmaf(am[i], bn[j], acc[i][j]);
        }
        __syncthreads();
    }
#pragma unroll
    for (int i = 0; i < 4; ++i) {
        *(float4*)(O + ((size_t)b * T4096 + s0 + m0 + i) * CH + c0) =
            make_float4(acc[i][0], acc[i][1], acc[i][2], acc[i][3]);
    }
}

// ---------------------------------------------------------------------------
// In-place L2 normalize over the 64 channels of each token (Q then K).
// One wave per token, both token-major. Butterfly order unchanged -> bit-exact.
// ---------------------------------------------------------------------------
__global__ __launch_bounds__(256) void normalize_qk(float* __restrict__ QT, float* __restrict__ KT)
{
    int gtok = blockIdx.x * 4 + (threadIdx.x >> 6);
    int lane = threadIdx.x & 63;
    float* base = (gtok < 8 * T4096) ? QT : KT;
    int t = gtok & (8 * T4096 - 1);
    float* p = base + (size_t)t * CH + lane;
    float v = *p;
    float ss = v * v;
#pragma unroll
    for (int off = 32; off; off >>= 1) ss += __shfl_xor(ss, off);
    float n = fmaxf(sqrtf(ss), 1e-12f);
    *p = v / n;
}

// ---------------------------------------------------------------------------
// Fused sim + top-9, v9: row-exclusive threads, K-row in 64 VGPRs.
// 512 blocks x 256 thr. wg decode: b = wg&7 (XCD affinity), sp = (wg>>3)&3
// (col split: 1024 cols), rt = wg>>5 (row tile: 256 rows). thread owns row
// rt*256+tid exclusively: K row in registers (zero K traffic in loop);
// Q addresses are wave-uniform -> one cacheline per load instruction
// (no L1 bandwidth wall, the R10 bottleneck). 4 cols in flight = 4
// independent 64-fma chains. Per-thread top-9 is exact (no merge/shfl;
// threshold = own 9th key). Partials (sorted 9-lists) -> PKv/PKi, merged
// by topk_merge. kr[] statically indexed via full c4g unroll (rule #20);
// launch_bounds(256,2) allows 256 VGPR (grid gives 2 waves/SIMD anyway).
// Chain per (row,s): c4g asc, xyzw, from 0.0f -> sims bit-identical;
// top-9 under (v desc, idx asc) is split/scan-order-invariant.
// ---------------------------------------------------------------------------
__global__ __launch_bounds__(256, 2) void sim_topk(
    const float* __restrict__ QT, const float* __restrict__ KT,
    unsigned* __restrict__ PKv, unsigned short* __restrict__ PKi)
{
    const int wg = blockIdx.x;
    const int b  = wg & 7;
    const int sp = (wg >> 3) & 3;
    const int rt = wg >> 5;                       // 0..15
    const int row = rt * 256 + threadIdx.x;

    float4 kr[16];
    const float* kp = KT + ((size_t)b * T4096 + row) * CH;
#pragma unroll
    for (int i = 0; i < 16; ++i) kr[i] = *(const float4*)(kp + 4 * i);

    u64 tv[9];
#pragma unroll
    for (int q = 0; q < 9; ++q) tv[q] = 0ULL;
    unsigned thr_hi = 0u;

    const float* qb = QT + ((size_t)b * T4096 + sp * 1024) * CH;

#pragma unroll 1
    for (int qs = 0; qs < 256; ++qs) {            // quads of 4 cols
        const float* base = qb + (size_t)qs * (4 * CH);
        float a0 = 0.f, a1 = 0.f, a2 = 0.f, a3 = 0.f;
#pragma unroll
        for (int c = 0; c < 16; ++c) {
            float4 q0 = *(const float4*)(base + c * 4);
            float4 q1 = *(const float4*)(base + CH + c * 4);
            float4 q2 = *(const float4*)(base + 2 * CH + c * 4);
            float4 q3 = *(const float4*)(base + 3 * CH + c * 4);
            a0 = fmaf(kr[c].x, q0.x, a0); a0 = fmaf(kr[c].y, q0.y, a0);
            a0 = fmaf(kr[c].z, q0.z, a0); a0 = fmaf(kr[c].w, q0.w, a0);
            a1 = fmaf(kr[c].x, q1.x, a1); a1 = fmaf(kr[c].y, q1.y, a1);
            a1 = fmaf(kr[c].z, q1.z, a1); a1 = fmaf(kr[c].w, q1.w, a1);
            a2 = fmaf(kr[c].x, q2.x, a2); a2 = fmaf(kr[c].y, q2.y, a2);
            a2 = fmaf(kr[c].z, q2.z, a2); a2 = fmaf(kr[c].w, q2.w, a2);
            a3 = fmaf(kr[c].x, q3.x, a3); a3 = fmaf(kr[c].y, q3.y, a3);
            a3 = fmaf(kr[c].z, q3.z, a3); a3 = fmaf(kr[c].w, q3.w, a3);
        }
        const int s0 = sp * 1024 + qs * 4;
        float av[4] = {a0, a1, a2, a3};
#pragma unroll
        for (int j = 0; j < 4; ++j) {
            float v = fmaxf(av[j], 0.f);          // clip BEFORE top-k (as ref)
            unsigned vb = __float_as_uint(v);
            if (vb >= thr_hi) {                   // cheap 32-bit pre-guard
                u64 key = ((u64)vb << 32) | (u64)(4095 - (s0 + j));
                if (key > tv[8]) {                // exact per-thread 9th
                    u64 cv = key;
#pragma unroll
                    for (int p = 0; p < 9; ++p) { // branchless sorted insert
                        u64 t  = tv[p];
                        bool g = cv > t;
                        tv[p] = g ? cv : t;
                        cv    = g ? t  : cv;
                    }
                    thr_hi = (unsigned)(tv[8] >> 32);
                }
            }
        }
    }

    const size_t o = (((size_t)b * 4 + sp) * T4096 + row) * 9;
#pragma unroll
    for (int q = 0; q < 9; ++q) {
        PKv[o + q] = (unsigned)(tv[q] >> 32);
        PKi[o + q] = (unsigned short)(tv[q] & 0xffffULL);
    }
}

// ---------------------------------------------------------------------------
// Merge the 4 per-split sorted 9-lists of each row into the final top-9.
// 32768 threads, one per (b,row). Early-break per split (lists sorted desc,
// keys unique). Order == (v desc, idx asc) == jax.lax.top_k.
// ---------------------------------------------------------------------------
__global__ __launch_bounds__(256) void topk_merge(
    const unsigned* __restrict__ PKv, const unsigned short* __restrict__ PKi,
    int* __restrict__ IDX)
{
    const int t = blockIdx.x * 256 + threadIdx.x;   // 0..32767
    const int b = t >> 12;
    const int row = t & 4095;

    u64 tv[9];
#pragma unroll
    for (int q = 0; q < 9; ++q) tv[q] = 0ULL;

    for (int sp = 0; sp < 4; ++sp) {
        const size_t o = (((size_t)b * 4 + sp) * T4096 + row) * 9;
#pragma unroll 1
        for (int q = 0; q < 9; ++q) {
            u64 key = ((u64)PKv[o + q] << 32) | (u64)PKi[o + q];
            if (key <= tv[8]) break;              // rest of this split is smaller
            u64 cv = key;
#pragma unroll
            for (int p = 0; p < 9; ++p) {
                u64 tt = tv[p];
                bool g = cv > tt;
                tv[p] = g ? cv : tt;
                cv    = g ? tt : cv;
            }
        }
    }

    int* dst = IDX + ((size_t)b * T4096 + row) * 9;
#pragma unroll
    for (int q = 0; q < 9; ++q)
        dst[q] = 4095 - (int)(unsigned)(tv[q] & 0xffffULL);
}

// ---------------------------------------------------------------------------
// conv_w [o][i][j] -> wT3 [j][i/4][o][4] for coalesced float4 lane loads
// ---------------------------------------------------------------------------
__global__ void transpose_w(const float* __restrict__ cw, float* __restrict__ wT3)
{
    int idx = blockIdx.x * 256 + threadIdx.x;
    if (idx >= 64 * 64 * 9) return;
    int q   = idx & 3;
    int o   = (idx >> 2) & 63;
    int i4g = (idx >> 8) & 15;
    int j   = idx >> 12;
    wT3[idx] = cw[o * 576 + (i4g * 4 + q) * 9 + j];
}

// ---------------------------------------------------------------------------
// gather + conv1d(K=9, stride 9) + bias. Wave = 4 tokens x 64 o-lanes.
// out1 layout [b][t][o] (coalesced write, transpose-free LDS load in gemm_out)
// ---------------------------------------------------------------------------
__global__ __launch_bounds__(256) void gather_conv(
    const float* __restrict__ VT, const int* __restrict__ IDX,
    const float* __restrict__ wT3, const float* __restrict__ conv_b,
    float* __restrict__ out1)
{
    const int b  = blockIdx.y;
    const int w  = threadIdx.x >> 6;
    const int o  = threadIdx.x & 63;
    const int t0 = (blockIdx.x * 4 + w) * 4;

    __shared__ float vv[4][4][9][64];
    __shared__ int   nb[4][36];

    if (o < 36) nb[w][o] = IDX[((size_t)b * T4096 + t0) * 9 + o];
    __syncthreads();

#pragma unroll
    for (int tok = 0; tok < 4; ++tok)
#pragma unroll
        for (int j = 0; j < 9; ++j) {
            int n = nb[w][tok * 9 + j];
            vv[w][tok][j][o] = VT[((size_t)b * T4096 + n) * CH + o];
        }
    __syncthreads();

    float cb = conv_b[o];
    float a0 = cb, a1 = cb, a2 = cb, a3 = cb;
    for (int j = 0; j < 9; ++j) {
#pragma unroll
        for (int i4 = 0; i4 < 16; ++i4) {
            float4 w4 = *(const float4*)(wT3 + (((size_t)j * 16 + i4) * 64 + o) * 4);
            float4 v0 = *(const float4*)&vv[w][0][j][i4 * 4];
            float4 v1 = *(const float4*)&vv[w][1][j][i4 * 4];
            float4 v2 = *(const float4*)&vv[w][2][j][i4 * 4];
            float4 v3 = *(const float4*)&vv[w][3][j][i4 * 4];
            a0 = fmaf(v0.x, w4.x, a0); a0 = fmaf(v0.y, w4.y, a0); a0 = fmaf(v0.z, w4.z, a0); a0 = fmaf(v0.w, w4.w, a0);
            a1 = fmaf(v1.x, w4.x, a1); a1 = fmaf(v1.y, w4.y, a1); a1 = fmaf(v1.z, w4.z, a1); a1 = fmaf(v1.w, w4.w, a1);
            a2 = fmaf(v2.x, w4.x, a2); a2 = fmaf(v2.y, w4.y, a2); a2 = fmaf(v2.z, w4.z, a2); a2 = fmaf(v2.w, w4.w, a2);
            a3 = fmaf(v3.x, w4.x, a3); a3 = fmaf(v3.y, w4.y, a3); a3 = fmaf(v3.z, w4.z, a3); a3 = fmaf(v3.w, w4.w, a3);
        }
    }
    out1[((size_t)b * T4096 + t0 + 0) * CH + o] = a0;
    out1[((size_t)b * T4096 + t0 + 1) * CH + o] = a1;
    out1[((size_t)b * T4096 + t0 + 2) * CH + o] = a2;
    out1[((size_t)b * T4096 + t0 + 3) * CH + o] = a3;
}

// ---------------------------------------------------------------------------
// Final: Out[b][c][s] = sum_t out1[b][t][c] * Wo[s][t]
// tile 64(c) x 64(s), K-step 64, 256 thr, 4x4 micro-tile. Grid 512 (2/CU).
// ---------------------------------------------------------------------------
__global__ __launch_bounds__(256) void gemm_out(
    const float* __restrict__ out1, const float* __restrict__ Wo, float* __restrict__ Out)
{
    const int b  = blockIdx.y;
    const int s0 = blockIdx.x * 64;
    __shared__ float As[64][68];    // [k][c]
    __shared__ float Bs[64][68];    // [k][s^swz]
    const int tid = threadIdx.x;
    const int tx = tid & 15;  const int sl = tx * 4;
    const int my = tid >> 4;  const int c0 = my * 4;
    const int lk = (tid & 7) * 4;
    const int sw = lk;

    float acc[4][4];
#pragma unroll
    for (int i = 0; i < 4; ++i)
#pragma unroll
        for (int j = 0; j < 4; ++j) acc[i][j] = 0.f;

    for (int k0 = 0; k0 < T4096; k0 += 64) {
        {   // A: out1 is [t][c] -> direct [k][c] copy, no transpose
            int r  = tid >> 2;              // 0..63
            int cL = (tid & 3) * 16;
            const float* src = out1 + ((size_t)b * T4096 + k0 + r) * CH + cL;
#pragma unroll
            for (int q = 0; q < 4; ++q)
                *(float4*)&As[r][cL + 4 * q] = *(const float4*)(src + 4 * q);
        }
#pragma unroll
        for (int kk = 0; kk < 2; ++kk) {    // B: Wo rows, swizzled scatter
            const int kb = 32 * kk + lk;
#pragma unroll
            for (int p = 0; p < 2; ++p) {
                int row = (tid >> 3) + 32 * p;   // 0..63 (s within tile)
                float4 v = *(const float4*)(Wo + (size_t)(s0 + row) * T4096 + k0 + kb);
                int col = row ^ sw;
                Bs[kb + 0][col] = v.x; Bs[kb + 1][col] = v.y;
                Bs[kb + 2][col] = v.z; Bs[kb + 3][col] = v.w;
            }
        }
        __syncthreads();
#pragma unroll
        for (int k = 0; k < 64; ++k) {
            const int swk = k & 28;
            float4 a  = *(const float4*)&As[k][c0];
            float4 bv = *(const float4*)&Bs[k][sl ^ swk];
            float av[4] = {a.x, a.y, a.z, a.w};
            float bn[4] = {bv.x, bv.y, bv.z, bv.w};
#pragma unroll
            for (int i = 0; i < 4; ++i)
#pragma unroll
                for (int j = 0; j < 4; ++j) acc[i][j] = fmaf(av[i], bn[j], acc[i][j]);
        }
        __syncthreads();
    }
#pragma unroll
    for (int i = 0; i < 4; ++i) {
        float* dst = Out + ((size_t)b * CH + c0 + i) * T4096 + s0 + sl;
        *(float4*)dst = make_float4(acc[i][0], acc[i][1], acc[i][2], acc[i][3]);
    }
}

// ---------------------------------------------------------------------------
extern "C" void kernel_launch(void* const* d_in, const int* in_sizes, int n_in,
                              void* d_out, int out_size, void* d_ws, size_t ws_size,
                              hipStream_t stream)
{
    const float* x  = (const float*)d_in[0];
    const float* Wq = (const float*)d_in[1];
    const float* Wk = (const float*)d_in[2];
    const float* Wv = (const float*)d_in[3];
    const float* Wo = (const float*)d_in[4];
    const float* cw = (const float*)d_in[5];
    const float* cb = (const float*)d_in[6];
    float* Out = (float*)d_out;

    char* ws = (char*)d_ws;
    float* QT   = (float*)(ws);                               // 8 MB  [b][s][c]
    float* KT   = (float*)(ws + (size_t)8  * 1024 * 1024);    // 8 MB  [b][s][c]
    float* VT   = (float*)(ws + (size_t)16 * 1024 * 1024);    // 8 MB  [b][s][c]
    int*   IDXb = (int*)  (ws + (size_t)24 * 1024 * 1024);    // 1.2 MB [b][t][9]
    float* wT3  = (float*)(ws + (size_t)26 * 1024 * 1024);    // 147 KB
    float* out1 = QT;   // QT dead after sim_topk; reuse as conv output [b][t][o]

    // Top-k split partials staged in d_out (dead until gemm_out rewrites it):
    unsigned*       PKv = (unsigned*)d_out;                              // 4.72 MB
    unsigned short* PKi = (unsigned short*)((char*)d_out + (size_t)5 * 1024 * 1024); // 2.36 MB

    gemm_qkv<<<dim3(32, 8, 3), dim3(512), 0, stream>>>(x, Wq, Wk, Wv, QT, KT, VT);
    normalize_qk<<<dim3(16384), dim3(256), 0, stream>>>(QT, KT);
    sim_topk<<<dim3(512), dim3(256), 0, stream>>>(QT, KT, PKv, PKi);
    topk_merge<<<dim3(128), dim3(256), 0, stream>>>(PKv, PKi, IDXb);
    transpose_w<<<dim3(144), dim3(256), 0, stream>>>(cw, wT3);
    gather_conv<<<dim3(256, 8), dim3(256), 0, stream>>>(VT, IDXb, wT3, cb, out1);
    gemm_out<<<dim3(64, 8), dim3(256), 0, stream>>>(out1, Wo, Out);
}

// Round 13
// 1703.030 us; speedup vs baseline: 1.0979x; 1.0979x over previous
//
#include <hip/hip_runtime.h>

#define T4096 4096
#define CH 64
typedef unsigned long long u64;

// ---------------------------------------------------------------------------
// QKV (exact R10): tile 128(s) x 64(c), K-step 64, 512 thr, 4x4 micro.
// LDS [k][col^swz], swizzle col = row ^ (k & 28). Q stored TILED:
// Qr2[b][blk=s/64][c4g][sl=s%64][4]. fmaf chain k-ascending -> bit-identical.
// ---------------------------------------------------------------------------
__global__ __launch_bounds__(512) void gemm_qkv(
    const float* __restrict__ X,
    const float* __restrict__ Wq, const float* __restrict__ Wk, const float* __restrict__ Wv,
    float* __restrict__ QT, float* __restrict__ KT, float* __restrict__ VT)
{
    const float* W = (blockIdx.z == 0) ? Wq : (blockIdx.z == 1) ? Wk : Wv;
    float*       O = (blockIdx.z == 0) ? QT : (blockIdx.z == 1) ? KT : VT;
    const int b  = blockIdx.y;
    const int s0 = blockIdx.x * 128;

    __shared__ float As[64][132];   // [k][m^swz]
    __shared__ float Bs[64][68];    // [k][c^swz]

    const int tid = threadIdx.x;
    const int tx = tid & 15;   const int c0 = tx * 4;
    const int my = tid >> 4;   const int m0 = my * 4;   // 0..124
    const int lr = tid >> 3;            // 0..63
    const int lk = (tid & 7) * 4;       // 0..28
    const int sw = lk;

    float acc[4][4];
#pragma unroll
    for (int i = 0; i < 4; ++i)
#pragma unroll
        for (int j = 0; j < 4; ++j) acc[i][j] = 0.f;

    const float* Xb = X + (size_t)b * CH * T4096;

    for (int k0 = 0; k0 < T4096; k0 += 64) {
#pragma unroll
        for (int kk = 0; kk < 2; ++kk) {
            const int kb = 32 * kk + lk;
#pragma unroll
            for (int p = 0; p < 2; ++p) {   // A: 128 rows
                int row = lr + 64 * p;
                float4 v = *(const float4*)(W + (size_t)(s0 + row) * T4096 + k0 + kb);
                int col = row ^ sw;
                As[kb + 0][col] = v.x; As[kb + 1][col] = v.y;
                As[kb + 2][col] = v.z; As[kb + 3][col] = v.w;
            }
            {   // B: 64 rows (channels)
                int row = lr;
                float4 v = *(const float4*)(Xb + (size_t)row * T4096 + k0 + kb);
                int col = row ^ sw;
                Bs[kb + 0][col] = v.x; Bs[kb + 1][col] = v.y;
                Bs[kb + 2][col] = v.z; Bs[kb + 3][col] = v.w;
            }
        }
        __syncthreads();
#pragma unroll
        for (int k = 0; k < 64; ++k) {
            const int swk = k & 28;
            float4 a  = *(const float4*)&As[k][m0 ^ swk];
            float4 bv = *(const float4*)&Bs[k][c0 ^ swk];
            float am[4] = {a.x, a.y, a.z, a.w};
            float bn[4] = {bv.x, bv.y, bv.z, bv.w};
#pragma unroll
            for (int i = 0; i < 4; ++i)
#pragma unroll
                for (int j = 0; j < 4; ++j) acc[i][j] = fmaf(am[i], bn[j], acc[i][j]);
        }
        __syncthreads();
    }
    if (blockIdx.z == 0) {
        // tiled store: Qr2[b][blk][c4g=tx][sl][4]
#pragma unroll
        for (int i = 0; i < 4; ++i) {
            int s = s0 + m0 + i;
            *(float4*)(O + ((((size_t)b * 64 + (s >> 6)) * 16 + tx) * 64 + (s & 63)) * 4) =
                make_float4(acc[i][0], acc[i][1], acc[i][2], acc[i][3]);
        }
    } else {
#pragma unroll
        for (int i = 0; i < 4; ++i) {
            *(float4*)(O + ((size_t)b * T4096 + s0 + m0 + i) * CH + c0) =
                make_float4(acc[i][0], acc[i][1], acc[i][2], acc[i][3]);
        }
    }
}

// ---------------------------------------------------------------------------
// In-place L2 normalize (exact R10). Q uses tiled layout; butterfly order
// unchanged -> bit-exact.
// ---------------------------------------------------------------------------
__global__ __launch_bounds__(256) void normalize_qk(float* __restrict__ QT, float* __restrict__ KT)
{
    int gtok = blockIdx.x * 4 + (threadIdx.x >> 6);
    int lane = threadIdx.x & 63;
    bool isQ = (gtok < 8 * T4096);
    int t = gtok & (T4096 - 1);
    int b = (gtok >> 12) & 7;
    float* p;
    if (isQ) p = QT + ((((size_t)b * 64 + (t >> 6)) * 16 + (lane >> 2)) * 64 + (t & 63)) * 4 + (lane & 3);
    else     p = KT + ((size_t)b * T4096 + t) * CH + lane;
    float v = *p;
    float ss = v * v;
#pragma unroll
    for (int off = 32; off; off >>= 1) ss += __shfl_xor(ss, off);
    float n = fmaxf(sqrtf(ss), 1e-12f);
    *p = v / n;
}

// ---------------------------------------------------------------------------
// sim_topk v11 "GEMM-topk, lock-free": block = 64 rows x all 4096 cols in
// 32 chunks of 128. LDS channel-major Kn[c][row'], Qs[c][col'] (XOR
// swizzles; stores 2-way max = free, reads broadcast/contiguous). Micro
// 4x4: 2 ds_read_b128 per 16 fma (GEMM-grade reuse; kills v8's L1 wall).
// Top-9: per-thread registers tv[4][9] (u64 keys (bits(v)<<32)|(4095-s));
// shared row threshold = max over 32 col-lanes of lane-9ths via shfl_xor,
// refreshed only when __any lane inserted (v8's proven exact-skip logic:
// candidate <= thr provably not in row top-9; keys unique). No LDS state,
// no locks (R12's deadlock eliminated). End: v8's 32-lane shfl merge.
// Chain per (row,col): c ascending from 0.0f == prior rounds' chain over
// identical values -> sims bit-identical; selection semantics == v8 ->
// IDX bit-identical.
// ---------------------------------------------------------------------------
__global__ __launch_bounds__(512, 2) void sim_topk(
    const float* __restrict__ Qr, const float* __restrict__ KT, int* __restrict__ IDX)
{
    const int wg = blockIdx.x;
    const int b  = wg & 7;              // XCD affinity
    const int r0 = (wg >> 3) * 64;

    __shared__ float Kn[64][68];        // [c][row ^ (((c>>3)&7)<<3)]
    __shared__ float Qs[64][132];       // [c][col ^ (((c>>4)&3)<<3)]

    const int tid  = threadIdx.x;
    const int colg = tid & 31;          // 32 col-groups x 4 = 128 cols/chunk
    const int rowg = tid >> 5;          // 16 row-groups x 4 = 64 rows

    {   // stage Kn (once), channel-major with row-XOR swizzle
        int row = tid >> 3;             // 0..63
        int c8  = (tid & 7) * 8;        // 0..56
        const float* src = KT + ((size_t)b * T4096 + r0 + row) * CH + c8;
        float4 v0 = *(const float4*)(src);
        float4 v1 = *(const float4*)(src + 4);
        int rp = row ^ ((tid & 7) << 3);    // ((c>>3)&7) == tid&7 for c in [c8,c8+8)
        Kn[c8 + 0][rp] = v0.x; Kn[c8 + 1][rp] = v0.y;
        Kn[c8 + 2][rp] = v0.z; Kn[c8 + 3][rp] = v0.w;
        Kn[c8 + 4][rp] = v1.x; Kn[c8 + 5][rp] = v1.y;
        Kn[c8 + 6][rp] = v1.z; Kn[c8 + 7][rp] = v1.w;
    }

    u64 tv[4][9];
#pragma unroll
    for (int r = 0; r < 4; ++r)
#pragma unroll
        for (int q = 0; q < 9; ++q) tv[r][q] = 0ULL;
    u64 thr[4] = {0ULL, 0ULL, 0ULL, 0ULL};
    unsigned thr_hi[4] = {0u, 0u, 0u, 0u};

    for (int chk = 0; chk < 32; ++chk) {
        const int c0 = chk * 128;
        __syncthreads();                // Qs reads of prev chunk complete
        {   // stage Qs chunk (transposed from tiled Q) with col-XOR swizzle
            int col  = tid >> 2;            // 0..127
            int cQ   = (tid & 3) * 16;      // 0..48
            int gcol = c0 + col;
            const float* qb = Qr + ((((size_t)b * 64 + (gcol >> 6)) * 16 + (cQ >> 2)) * 64
                                    + (gcol & 63)) * 4;
            int cp = col ^ ((cQ >> 4) << 3);    // ((c>>4)&3) == cQ>>4 for c in [cQ,cQ+16)
#pragma unroll
            for (int i = 0; i < 4; ++i) {
                float4 v = *(const float4*)(qb + (size_t)i * 256);
                int c = cQ + i * 4;
                Qs[c + 0][cp] = v.x; Qs[c + 1][cp] = v.y;
                Qs[c + 2][cp] = v.z; Qs[c + 3][cp] = v.w;
            }
        }
        __syncthreads();

        float acc[4][4];
#pragma unroll
        for (int i = 0; i < 4; ++i)
#pragma unroll
            for (int j = 0; j < 4; ++j) acc[i][j] = 0.f;

#pragma unroll 8
        for (int c = 0; c < 64; ++c) {
            const int g8 = ((c >> 3) & 7) << 3;
            const int g4 = ((c >> 4) & 3) << 3;
            float4 kv = *(const float4*)&Kn[c][(rowg * 4) ^ g8];
            float4 qv = *(const float4*)&Qs[c][(colg * 4) ^ g4];
            float km[4] = {kv.x, kv.y, kv.z, kv.w};
            float qm[4] = {qv.x, qv.y, qv.z, qv.w};
#pragma unroll
            for (int i = 0; i < 4; ++i)
#pragma unroll
                for (int j = 0; j < 4; ++j)
                    acc[i][j] = fmaf(km[i], qm[j], acc[i][j]);
        }

        // guard + rare insert (per-thread registers, v8 semantics)
        bool ins = false;
#pragma unroll
        for (int i = 0; i < 4; ++i)
#pragma unroll
            for (int j = 0; j < 4; ++j) {
                float v = fmaxf(acc[i][j], 0.f);       // clip BEFORE top-k (as ref)
                unsigned vb = __float_as_uint(v);
                if (vb >= thr_hi[i]) {                 // cheap 32-bit pre-guard
                    int s = c0 + colg * 4 + j;
                    u64 key = ((u64)vb << 32) | (u64)(4095 - s);
                    if (key > thr[i]) {                // exact guard
                        u64 cv = key;
#pragma unroll
                        for (int p = 0; p < 9; ++p) {  // branchless sorted insert
                            u64 t  = tv[i][p];
                            bool g = cv > t;
                            tv[i][p] = g ? cv : t;
                            cv       = g ? t  : cv;
                        }
                        ins = true;
                    }
                }
            }
        if (__any(ins)) {   // refresh row lower bounds (max of lane 9ths)
#pragma unroll
            for (int r = 0; r < 4; ++r) {
                u64 m = tv[r][8];
#pragma unroll
                for (int msk = 1; msk < 32; msk <<= 1) {
                    u64 o = __shfl_xor(m, msk);
                    if (o > m) m = o;
                }
                thr[r] = m;
                thr_hi[r] = (unsigned)(m >> 32);
            }
        }
    }

    // in-wave merge: the 32 col-lanes sharing rowg hold partial 9-lists for
    // row r0 + rowg*4 + i. 9 selection rounds of 32-lane xor-reduce.
#pragma unroll
    for (int i = 0; i < 4; ++i) {
        u64 mv[9];
#pragma unroll
        for (int q = 0; q < 9; ++q) mv[q] = tv[i][q];
        const int outrow = r0 + rowg * 4 + i;
        int* dst = IDX + ((size_t)b * T4096 + outrow) * 9;
        for (int sel = 0; sel < 9; ++sel) {
            u64 bk = mv[0]; int bl = colg;
#pragma unroll
            for (int m = 1; m < 32; m <<= 1) {
                u64 ok = __shfl_xor(bk, m);
                int ol = __shfl_xor(bl, m);
                if (ok > bk) { bk = ok; bl = ol; }
            }
            if (colg == 0) dst[sel] = 4095 - (int)(unsigned)(bk & 0xffffULL);
            if (colg == bl) {   // consume winner: static shift
#pragma unroll
                for (int q = 0; q < 8; ++q) mv[q] = mv[q + 1];
                mv[8] = 0ULL;
            }
        }
    }
}

// ---------------------------------------------------------------------------
// conv_w [o][i][j] -> wT3 [j][i/4][o][4] for coalesced float4 lane loads
// ---------------------------------------------------------------------------
__global__ void transpose_w(const float* __restrict__ cw, float* __restrict__ wT3)
{
    int idx = blockIdx.x * 256 + threadIdx.x;
    if (idx >= 64 * 64 * 9) return;
    int q   = idx & 3;
    int o   = (idx >> 2) & 63;
    int i4g = (idx >> 8) & 15;
    int j   = idx >> 12;
    wT3[idx] = cw[o * 576 + (i4g * 4 + q) * 9 + j];
}

// ---------------------------------------------------------------------------
// gather + conv1d(K=9, stride 9) + bias (exact R10).
// ---------------------------------------------------------------------------
__global__ __launch_bounds__(256) void gather_conv(
    const float* __restrict__ VT, const int* __restrict__ IDX,
    const float* __restrict__ wT3, const float* __restrict__ conv_b,
    float* __restrict__ out1)
{
    const int b  = blockIdx.y;
    const int w  = threadIdx.x >> 6;
    const int o  = threadIdx.x & 63;
    const int t0 = (blockIdx.x * 4 + w) * 4;

    __shared__ float vv[4][4][9][64];
    __shared__ int   nb[4][36];

    if (o < 36) nb[w][o] = IDX[((size_t)b * T4096 + t0) * 9 + o];
    __syncthreads();

#pragma unroll
    for (int tok = 0; tok < 4; ++tok)
#pragma unroll
        for (int j = 0; j < 9; ++j) {
            int n = nb[w][tok * 9 + j];
            vv[w][tok][j][o] = VT[((size_t)b * T4096 + n) * CH + o];
        }
    __syncthreads();

    float cb = conv_b[o];
    float a0 = cb, a1 = cb, a2 = cb, a3 = cb;
    for (int j = 0; j < 9; ++j) {
#pragma unroll
        for (int i4 = 0; i4 < 16; ++i4) {
            float4 w4 = *(const float4*)(wT3 + (((size_t)j * 16 + i4) * 64 + o) * 4);
            float4 v0 = *(const float4*)&vv[w][0][j][i4 * 4];
            float4 v1 = *(const float4*)&vv[w][1][j][i4 * 4];
            float4 v2 = *(const float4*)&vv[w][2][j][i4 * 4];
            float4 v3 = *(const float4*)&vv[w][3][j][i4 * 4];
            a0 = fmaf(v0.x, w4.x, a0); a0 = fmaf(v0.y, w4.y, a0); a0 = fmaf(v0.z, w4.z, a0); a0 = fmaf(v0.w, w4.w, a0);
            a1 = fmaf(v1.x, w4.x, a1); a1 = fmaf(v1.y, w4.y, a1); a1 = fmaf(v1.z, w4.z, a1); a1 = fmaf(v1.w, w4.w, a1);
            a2 = fmaf(v2.x, w4.x, a2); a2 = fmaf(v2.y, w4.y, a2); a2 = fmaf(v2.z, w4.z, a2); a2 = fmaf(v2.w, w4.w, a2);
            a3 = fmaf(v3.x, w4.x, a3); a3 = fmaf(v3.y, w4.y, a3); a3 = fmaf(v3.z, w4.z, a3); a3 = fmaf(v3.w, w4.w, a3);
        }
    }
    out1[((size_t)b * T4096 + t0 + 0) * CH + o] = a0;
    out1[((size_t)b * T4096 + t0 + 1) * CH + o] = a1;
    out1[((size_t)b * T4096 + t0 + 2) * CH + o] = a2;
    out1[((size_t)b * T4096 + t0 + 3) * CH + o] = a3;
}

// ---------------------------------------------------------------------------
// Final GEMM (exact R10): tile 64x64, K-step 64, 256 thr, 4x4 micro.
// ---------------------------------------------------------------------------
__global__ __launch_bounds__(256) void gemm_out(
    const float* __restrict__ out1, const float* __restrict__ Wo, float* __restrict__ Out)
{
    const int b  = blockIdx.y;
    const int s0 = blockIdx.x * 64;
    __shared__ float As[64][68];    // [k][c]
    __shared__ float Bs[64][68];    // [k][s^swz]
    const int tid = threadIdx.x;
    const int tx = tid & 15;  const int sl = tx * 4;
    const int my = tid >> 4;  const int c0 = my * 4;
    const int lk = (tid & 7) * 4;
    const int sw = lk;

    float acc[4][4];
#pragma unroll
    for (int i = 0; i < 4; ++i)
#pragma unroll
        for (int j = 0; j < 4; ++j) acc[i][j] = 0.f;

    for (int k0 = 0; k0 < T4096; k0 += 64) {
        {   // A: out1 [t][c] -> [k][c]
            int r  = tid >> 2;
            int cL = (tid & 3) * 16;
            const float* src = out1 + ((size_t)b * T4096 + k0 + r) * CH + cL;
#pragma unroll
            for (int q = 0; q < 4; ++q)
                *(float4*)&As[r][cL + 4 * q] = *(const float4*)(src + 4 * q);
        }
#pragma unroll
        for (int kk = 0; kk < 2; ++kk) {
            const int kb = 32 * kk + lk;
#pragma unroll
            for (int p = 0; p < 2; ++p) {
                int row = (tid >> 3) + 32 * p;
                float4 v = *(const float4*)(Wo + (size_t)(s0 + row) * T4096 + k0 + kb);
                int col = row ^ sw;
                Bs[kb + 0][col] = v.x; Bs[kb + 1][col] = v.y;
                Bs[kb + 2][col] = v.z; Bs[kb + 3][col] = v.w;
            }
        }
        __syncthreads();
#pragma unroll
        for (int k = 0; k < 64; ++k) {
            const int swk = k & 28;
            float4 a  = *(const float4*)&As[k][c0];
            float4 bv = *(const float4*)&Bs[k][sl ^ swk];
            float av[4] = {a.x, a.y, a.z, a.w};
            float bn[4] = {bv.x, bv.y, bv.z, bv.w};
#pragma unroll
            for (int i = 0; i < 4; ++i)
#pragma unroll
                for (int j = 0; j < 4; ++j) acc[i][j] = fmaf(av[i], bn[j], acc[i][j]);
        }
        __syncthreads();
    }
#pragma unroll
    for (int i = 0; i < 4; ++i) {
        float* dst = Out + ((size_t)b * CH + c0 + i) * T4096 + s0 + sl;
        *(float4*)dst = make_float4(acc[i][0], acc[i][1], acc[i][2], acc[i][3]);
    }
}

// ---------------------------------------------------------------------------
extern "C" void kernel_launch(void* const* d_in, const int* in_sizes, int n_in,
                              void* d_out, int out_size, void* d_ws, size_t ws_size,
                              hipStream_t stream)
{
    const float* x  = (const float*)d_in[0];
    const float* Wq = (const float*)d_in[1];
    const float* Wk = (const float*)d_in[2];
    const float* Wv = (const float*)d_in[3];
    const float* Wo = (const float*)d_in[4];
    const float* cw = (const float*)d_in[5];
    const float* cb = (const float*)d_in[6];
    float* Out = (float*)d_out;

    char* ws = (char*)d_ws;
    float* QT   = (float*)(ws);                               // 8 MB  Q tiled [b][blk][c4g][sl][4]
    float* KT   = (float*)(ws + (size_t)8  * 1024 * 1024);    // 8 MB  [b][s][c]
    float* VT   = (float*)(ws + (size_t)16 * 1024 * 1024);    // 8 MB  [b][s][c]
    int*   IDXb = (int*)  (ws + (size_t)24 * 1024 * 1024);    // 1.2 MB [b][t][9]
    float* wT3  = (float*)(ws + (size_t)26 * 1024 * 1024);    // 147 KB
    float* out1 = QT;   // QT dead after sim_topk; reuse as conv output [b][t][o]

    gemm_qkv<<<dim3(32, 8, 3), dim3(512), 0, stream>>>(x, Wq, Wk, Wv, QT, KT, VT);
    normalize_qk<<<dim3(16384), dim3(256), 0, stream>>>(QT, KT);
    sim_topk<<<dim3(512), dim3(512), 0, stream>>>(QT, KT, IDXb);
    transpose_w<<<dim3(144), dim3(256), 0, stream>>>(cw, wT3);
    gather_conv<<<dim3(256, 8), dim3(256), 0, stream>>>(VT, IDXb, wT3, cb, out1);
    gemm_out<<<dim3(64, 8), dim3(256), 0, stream>>>(out1, Wo, Out);
}

// Round 14
// 1592.482 us; speedup vs baseline: 1.1741x; 1.0694x over previous
//
#include <hip/hip_runtime.h>

#define T4096 4096
#define CH 64
typedef unsigned long long u64;
typedef float v2f __attribute__((ext_vector_type(2)));

// ---------------------------------------------------------------------------
// QKV + fused L2-normalize: O[b][s][c] = sum_t W[s][t] * X[b][c][t].
// tile 128(s) x 64(c), K-step 64, 512 thr, 4x4 micro (packed: acc2[4][2] v2f).
// Inner uses v_pk_fma_f32-style packed fma across the 2-col pairs; each
// output's chain is still scalar fma, k-ascending -> bit-identical.
// Epilogue (z<2) replicates normalize_qk's 64-lane butterfly EXACTLY:
// c = 4*tx + j; offs 32,16,8,4 -> shfl_xor over tx (8,4,2,1); offs 2,1 ->
// local j^2, j^1 pairs; n = fmax(sqrt(ss),1e-12); store v/n.
// Q stored CHANNEL-MAJOR QC[b][c][s] (for sim's packed col loads);
// K,V token-major [b][s][c]. K normalized, V raw.
// ---------------------------------------------------------------------------
__global__ __launch_bounds__(512) void gemm_qkv(
    const float* __restrict__ X,
    const float* __restrict__ Wq, const float* __restrict__ Wk, const float* __restrict__ Wv,
    float* __restrict__ QC, float* __restrict__ KT, float* __restrict__ VT)
{
    const float* W = (blockIdx.z == 0) ? Wq : (blockIdx.z == 1) ? Wk : Wv;
    float*       O = (blockIdx.z == 0) ? QC : (blockIdx.z == 1) ? KT : VT;
    const int b  = blockIdx.y;
    const int s0 = blockIdx.x * 128;

    __shared__ float As[64][132];   // [k][m^swz]
    __shared__ float Bs[64][68];    // [k][c^swz]

    const int tid = threadIdx.x;
    const int tx = tid & 15;   const int c0 = tx * 4;
    const int my = tid >> 4;   const int m0 = my * 4;   // 0..124
    const int lr = tid >> 3;            // 0..63
    const int lk = (tid & 7) * 4;       // 0..28
    const int sw = lk;

    v2f acc2[4][2];
#pragma unroll
    for (int i = 0; i < 4; ++i) { acc2[i][0] = (v2f)0.f; acc2[i][1] = (v2f)0.f; }

    const float* Xb = X + (size_t)b * CH * T4096;

    for (int k0 = 0; k0 < T4096; k0 += 64) {
#pragma unroll
        for (int kk = 0; kk < 2; ++kk) {
            const int kb = 32 * kk + lk;
#pragma unroll
            for (int p = 0; p < 2; ++p) {   // A: 128 rows
                int row = lr + 64 * p;
                float4 v = *(const float4*)(W + (size_t)(s0 + row) * T4096 + k0 + kb);
                int col = row ^ sw;
                As[kb + 0][col] = v.x; As[kb + 1][col] = v.y;
                As[kb + 2][col] = v.z; As[kb + 3][col] = v.w;
            }
            {   // B: 64 rows (channels)
                int row = lr;
                float4 v = *(const float4*)(Xb + (size_t)row * T4096 + k0 + kb);
                int col = row ^ sw;
                Bs[kb + 0][col] = v.x; Bs[kb + 1][col] = v.y;
                Bs[kb + 2][col] = v.z; Bs[kb + 3][col] = v.w;
            }
        }
        __syncthreads();
#pragma unroll
        for (int k = 0; k < 64; ++k) {
            const int swk = k & 28;
            float4 a  = *(const float4*)&As[k][m0 ^ swk];
            float4 bv = *(const float4*)&Bs[k][c0 ^ swk];
            v2f b0 = {bv.x, bv.y};
            v2f b1 = {bv.z, bv.w};
            float am[4] = {a.x, a.y, a.z, a.w};
#pragma unroll
            for (int i = 0; i < 4; ++i) {
                v2f as = {am[i], am[i]};
                acc2[i][0] = __builtin_elementwise_fma(as, b0, acc2[i][0]);
                acc2[i][1] = __builtin_elementwise_fma(as, b1, acc2[i][1]);
            }
        }
        __syncthreads();
    }

    if (blockIdx.z == 2) {
        // V: raw, token-major
#pragma unroll
        for (int i = 0; i < 4; ++i) {
            *(float4*)(O + ((size_t)b * T4096 + s0 + m0 + i) * CH + c0) =
                make_float4(acc2[i][0].x, acc2[i][0].y, acc2[i][1].x, acc2[i][1].y);
        }
        return;
    }

    // fused normalize (bit-exact butterfly replica)
    float nrm[4];
#pragma unroll
    for (int i = 0; i < 4; ++i) {
        float p0 = acc2[i][0].x * acc2[i][0].x;
        float p1 = acc2[i][0].y * acc2[i][0].y;
        float p2 = acc2[i][1].x * acc2[i][1].x;
        float p3 = acc2[i][1].y * acc2[i][1].y;
        p0 += __shfl_xor(p0, 8); p1 += __shfl_xor(p1, 8);
        p2 += __shfl_xor(p2, 8); p3 += __shfl_xor(p3, 8);
        p0 += __shfl_xor(p0, 4); p1 += __shfl_xor(p1, 4);
        p2 += __shfl_xor(p2, 4); p3 += __shfl_xor(p3, 4);
        p0 += __shfl_xor(p0, 2); p1 += __shfl_xor(p1, 2);
        p2 += __shfl_xor(p2, 2); p3 += __shfl_xor(p3, 2);
        p0 += __shfl_xor(p0, 1); p1 += __shfl_xor(p1, 1);
        p2 += __shfl_xor(p2, 1); p3 += __shfl_xor(p3, 1);
        float r0 = p0 + p2;     // c^2 pairing
        float r1 = p1 + p3;
        float ss = r0 + r1;     // c^1 pairing
        nrm[i] = fmaxf(sqrtf(ss), 1e-12f);
    }

    if (blockIdx.z == 0) {
        // Q: normalized, CHANNEL-major QC[b][c][s]; per j a float4 over tokens
        float vj[4][4];
#pragma unroll
        for (int i = 0; i < 4; ++i) {
            vj[0][i] = acc2[i][0].x / nrm[i];
            vj[1][i] = acc2[i][0].y / nrm[i];
            vj[2][i] = acc2[i][1].x / nrm[i];
            vj[3][i] = acc2[i][1].y / nrm[i];
        }
#pragma unroll
        for (int j = 0; j < 4; ++j) {
            *(float4*)(O + ((size_t)b * CH + c0 + j) * T4096 + s0 + m0) =
                make_float4(vj[j][0], vj[j][1], vj[j][2], vj[j][3]);
        }
    } else {
        // K: normalized, token-major
#pragma unroll
        for (int i = 0; i < 4; ++i) {
            *(float4*)(O + ((size_t)b * T4096 + s0 + m0 + i) * CH + c0) =
                make_float4(acc2[i][0].x / nrm[i], acc2[i][0].y / nrm[i],
                            acc2[i][1].x / nrm[i], acc2[i][1].y / nrm[i]);
        }
    }
}

// ---------------------------------------------------------------------------
// Fused sim + top-9, v13: v8 selection semantics + packed fma + chunk-max
// pre-guard. 1024 blocks x 512 thr; b = wg&7 (XCD affinity), 32 rows/block.
// thread(tx=tid&31, ty=tid>>5): rows {ty, 16+ty}, cols chk*256 + tx*8 + 0..7
// (contiguous -> packed col-pairs from float4 halves). Per channel:
// 8 pk-fma (2 rows x 4 col-pairs) + 2 splats; each output keeps its own
// scalar c-ascending fma chain -> sims bit-identical.
// Chunk-max guard: skip a row's 8 candidates iff max(clip(acc)) < thr value
// (strict; ties enter) -> exact. Inside: v8's per-candidate guard + insert,
// u64 keys (bits(v)<<32)|(4095-s), shared row thr via shfl_xor refresh on
// __any(ins). Merge: v8's 32-lane shfl merge. IDX bit-identical.
// ---------------------------------------------------------------------------
__global__ __launch_bounds__(512) void sim_topk(
    const float* __restrict__ QC, const float* __restrict__ KT, int* __restrict__ IDX)
{
    const int wg = blockIdx.x;
    const int b  = wg & 7;              // XCD affinity
    const int t0 = (wg >> 3) * 32;

    __shared__ float Kn[32][68];

    const int tid = threadIdx.x;
    const int tx = tid & 31;
    const int ty = tid >> 5;            // 0..15

    {   // stage 32 rows x 64 floats (normalized K, token-major)
        int row = tid >> 4; int cc = (tid & 15) * 4;
        *(float4*)&Kn[row][cc] =
            *(const float4*)(KT + ((size_t)b * T4096 + t0 + row) * CH + cc);
    }
    __syncthreads();

    u64 tv[2][9];
#pragma unroll
    for (int r = 0; r < 2; ++r)
#pragma unroll
        for (int q = 0; q < 9; ++q) tv[r][q] = 0ULL;
    u64 thr[2] = {0ULL, 0ULL};
    unsigned thr_hi[2] = {0u, 0u};

    const float* qcb = QC + (size_t)b * CH * T4096 + tx * 8;

    for (int chk = 0; chk < 16; ++chk) {
        const int cbase = chk * 256;
        const float* qk = qcb + cbase;

        v2f acc2[2][4];
#pragma unroll
        for (int m = 0; m < 4; ++m) { acc2[0][m] = (v2f)0.f; acc2[1][m] = (v2f)0.f; }

#pragma unroll 2
        for (int c4g = 0; c4g < 16; ++c4g) {
            float4 kv0 = *(const float4*)&Kn[ty][c4g * 4];
            float4 kv1 = *(const float4*)&Kn[16 + ty][c4g * 4];
            float km0[4] = {kv0.x, kv0.y, kv0.z, kv0.w};
            float km1[4] = {kv1.x, kv1.y, kv1.z, kv1.w};
#pragma unroll
            for (int cs = 0; cs < 4; ++cs) {
                const float* qp = qk + (size_t)(c4g * 4 + cs) * T4096;
                float4 qa = *(const float4*)(qp);
                float4 qb = *(const float4*)(qp + 4);
                v2f q0 = {qa.x, qa.y};
                v2f q1 = {qa.z, qa.w};
                v2f q2 = {qb.x, qb.y};
                v2f q3 = {qb.z, qb.w};
                v2f k0 = {km0[cs], km0[cs]};
                v2f k1 = {km1[cs], km1[cs]};
                acc2[0][0] = __builtin_elementwise_fma(k0, q0, acc2[0][0]);
                acc2[0][1] = __builtin_elementwise_fma(k0, q1, acc2[0][1]);
                acc2[0][2] = __builtin_elementwise_fma(k0, q2, acc2[0][2]);
                acc2[0][3] = __builtin_elementwise_fma(k0, q3, acc2[0][3]);
                acc2[1][0] = __builtin_elementwise_fma(k1, q0, acc2[1][0]);
                acc2[1][1] = __builtin_elementwise_fma(k1, q1, acc2[1][1]);
                acc2[1][2] = __builtin_elementwise_fma(k1, q2, acc2[1][2]);
                acc2[1][3] = __builtin_elementwise_fma(k1, q3, acc2[1][3]);
            }
        }

        bool ins = false;
#pragma unroll
        for (int rr = 0; rr < 2; ++rr) {
            v2f m01 = __builtin_elementwise_max(acc2[rr][0], acc2[rr][1]);
            v2f m23 = __builtin_elementwise_max(acc2[rr][2], acc2[rr][3]);
            v2f mm  = __builtin_elementwise_max(m01, m23);
            float vmax = fmaxf(fmaxf(mm.x, mm.y), 0.f);
            // skip iff vmax < thr value (strict): no candidate can beat;
            // ties (==) still enter for index-order resolution. Exact.
            if (!(vmax < __uint_as_float(thr_hi[rr]))) {
#pragma unroll
                for (int m = 0; m < 4; ++m)
#pragma unroll
                    for (int h = 0; h < 2; ++h) {
                        float v = fmaxf(h ? acc2[rr][m].y : acc2[rr][m].x, 0.f);
                        unsigned vb = __float_as_uint(v);
                        if (vb >= thr_hi[rr]) {            // v8 pre-guard
                            int s = cbase + tx * 8 + 2 * m + h;
                            u64 key = ((u64)vb << 32) | (u64)(4095 - s);
                            if (key > thr[rr]) {           // exact guard
                                u64 cv = key;
#pragma unroll
                                for (int p = 0; p < 9; ++p) {
                                    u64 t  = tv[rr][p];
                                    bool g = cv > t;
                                    tv[rr][p] = g ? cv : t;
                                    cv       = g ? t  : cv;
                                }
                                ins = true;
                            }
                        }
                    }
            }
        }
        if (__any(ins)) {   // refresh row lower bounds (max of lane 9ths)
#pragma unroll
            for (int r = 0; r < 2; ++r) {
                u64 m = tv[r][8];
#pragma unroll
                for (int msk = 1; msk < 32; msk <<= 1) {
                    u64 o = __shfl_xor(m, msk);
                    if (o > m) m = o;
                }
                thr[r] = m;
                thr_hi[r] = (unsigned)(m >> 32);
            }
        }
    }

    // in-wave merge: 32 col-lanes sharing ty hold partial 9-lists for row
    // rr*16+ty. 9 selection rounds of 32-lane xor-reduce on u64 keys.
#pragma unroll
    for (int rr = 0; rr < 2; ++rr) {
        u64 mv[9];
#pragma unroll
        for (int q = 0; q < 9; ++q) mv[q] = tv[rr][q];
        const int outrow = t0 + rr * 16 + ty;
        int* dst = IDX + ((size_t)b * T4096 + outrow) * 9;
        for (int sel = 0; sel < 9; ++sel) {
            u64 bk = mv[0]; int bl = tx;
#pragma unroll
            for (int m = 1; m < 32; m <<= 1) {
                u64 ok = __shfl_xor(bk, m);
                int ol = __shfl_xor(bl, m);
                if (ok > bk) { bk = ok; bl = ol; }
            }
            if (tx == 0) dst[sel] = 4095 - (int)(unsigned)(bk & 0xffffULL);
            if (tx == bl) {   // consume winner: static shift
#pragma unroll
                for (int q = 0; q < 8; ++q) mv[q] = mv[q + 1];
                mv[8] = 0ULL;
            }
        }
    }
}

// ---------------------------------------------------------------------------
// conv_w [o][i][j] -> wT3 [j][i/4][o][4] for coalesced float4 lane loads
// ---------------------------------------------------------------------------
__global__ void transpose_w(const float* __restrict__ cw, float* __restrict__ wT3)
{
    int idx = blockIdx.x * 256 + threadIdx.x;
    if (idx >= 64 * 64 * 9) return;
    int q   = idx & 3;
    int o   = (idx >> 2) & 63;
    int i4g = (idx >> 8) & 15;
    int j   = idx >> 12;
    wT3[idx] = cw[o * 576 + (i4g * 4 + q) * 9 + j];
}

// ---------------------------------------------------------------------------
// gather + conv1d(K=9, stride 9) + bias (exact R10).
// ---------------------------------------------------------------------------
__global__ __launch_bounds__(256) void gather_conv(
    const float* __restrict__ VT, const int* __restrict__ IDX,
    const float* __restrict__ wT3, const float* __restrict__ conv_b,
    float* __restrict__ out1)
{
    const int b  = blockIdx.y;
    const int w  = threadIdx.x >> 6;
    const int o  = threadIdx.x & 63;
    const int t0 = (blockIdx.x * 4 + w) * 4;

    __shared__ float vv[4][4][9][64];
    __shared__ int   nb[4][36];

    if (o < 36) nb[w][o] = IDX[((size_t)b * T4096 + t0) * 9 + o];
    __syncthreads();

#pragma unroll
    for (int tok = 0; tok < 4; ++tok)
#pragma unroll
        for (int j = 0; j < 9; ++j) {
            int n = nb[w][tok * 9 + j];
            vv[w][tok][j][o] = VT[((size_t)b * T4096 + n) * CH + o];
        }
    __syncthreads();

    float cb = conv_b[o];
    float a0 = cb, a1 = cb, a2 = cb, a3 = cb;
    for (int j = 0; j < 9; ++j) {
#pragma unroll
        for (int i4 = 0; i4 < 16; ++i4) {
            float4 w4 = *(const float4*)(wT3 + (((size_t)j * 16 + i4) * 64 + o) * 4);
            float4 v0 = *(const float4*)&vv[w][0][j][i4 * 4];
            float4 v1 = *(const float4*)&vv[w][1][j][i4 * 4];
            float4 v2 = *(const float4*)&vv[w][2][j][i4 * 4];
            float4 v3 = *(const float4*)&vv[w][3][j][i4 * 4];
            a0 = fmaf(v0.x, w4.x, a0); a0 = fmaf(v0.y, w4.y, a0); a0 = fmaf(v0.z, w4.z, a0); a0 = fmaf(v0.w, w4.w, a0);
            a1 = fmaf(v1.x, w4.x, a1); a1 = fmaf(v1.y, w4.y, a1); a1 = fmaf(v1.z, w4.z, a1); a1 = fmaf(v1.w, w4.w, a1);
            a2 = fmaf(v2.x, w4.x, a2); a2 = fmaf(v2.y, w4.y, a2); a2 = fmaf(v2.z, w4.z, a2); a2 = fmaf(v2.w, w4.w, a2);
            a3 = fmaf(v3.x, w4.x, a3); a3 = fmaf(v3.y, w4.y, a3); a3 = fmaf(v3.z, w4.z, a3); a3 = fmaf(v3.w, w4.w, a3);
        }
    }
    out1[((size_t)b * T4096 + t0 + 0) * CH + o] = a0;
    out1[((size_t)b * T4096 + t0 + 1) * CH + o] = a1;
    out1[((size_t)b * T4096 + t0 + 2) * CH + o] = a2;
    out1[((size_t)b * T4096 + t0 + 3) * CH + o] = a3;
}

// ---------------------------------------------------------------------------
// Final GEMM: tile 64x64, K-step 64, 256 thr, 4x4 micro (packed pairs).
// Per-output chain k-ascending -> bit-identical.
// ---------------------------------------------------------------------------
__global__ __launch_bounds__(256) void gemm_out(
    const float* __restrict__ out1, const float* __restrict__ Wo, float* __restrict__ Out)
{
    const int b  = blockIdx.y;
    const int s0 = blockIdx.x * 64;
    __shared__ float As[64][68];    // [k][c]
    __shared__ float Bs[64][68];    // [k][s^swz]
    const int tid = threadIdx.x;
    const int tx = tid & 15;  const int sl = tx * 4;
    const int my = tid >> 4;  const int c0 = my * 4;
    const int lk = (tid & 7) * 4;
    const int sw = lk;

    v2f acc2[4][2];
#pragma unroll
    for (int i = 0; i < 4; ++i) { acc2[i][0] = (v2f)0.f; acc2[i][1] = (v2f)0.f; }

    for (int k0 = 0; k0 < T4096; k0 += 64) {
        {   // A: out1 [t][c] -> [k][c]
            int r  = tid >> 2;
            int cL = (tid & 3) * 16;
            const float* src = out1 + ((size_t)b * T4096 + k0 + r) * CH + cL;
#pragma unroll
            for (int q = 0; q < 4; ++q)
                *(float4*)&As[r][cL + 4 * q] = *(const float4*)(src + 4 * q);
        }
#pragma unroll
        for (int kk = 0; kk < 2; ++kk) {
            const int kb = 32 * kk + lk;
#pragma unroll
            for (int p = 0; p < 2; ++p) {
                int row = (tid >> 3) + 32 * p;
                float4 v = *(const float4*)(Wo + (size_t)(s0 + row) * T4096 + k0 + kb);
                int col = row ^ sw;
                Bs[kb + 0][col] = v.x; Bs[kb + 1][col] = v.y;
                Bs[kb + 2][col] = v.z; Bs[kb + 3][col] = v.w;
            }
        }
        __syncthreads();
#pragma unroll
        for (int k = 0; k < 64; ++k) {
            const int swk = k & 28;
            float4 a  = *(const float4*)&As[k][c0];
            float4 bv = *(const float4*)&Bs[k][sl ^ swk];
            v2f b0 = {bv.x, bv.y};
            v2f b1 = {bv.z, bv.w};
            float av[4] = {a.x, a.y, a.z, a.w};
#pragma unroll
            for (int i = 0; i < 4; ++i) {
                v2f as = {av[i], av[i]};
                acc2[i][0] = __builtin_elementwise_fma(as, b0, acc2[i][0]);
                acc2[i][1] = __builtin_elementwise_fma(as, b1, acc2[i][1]);
            }
        }
        __syncthreads();
    }
#pragma unroll
    for (int i = 0; i < 4; ++i) {
        float* dst = Out + ((size_t)b * CH + c0 + i) * T4096 + s0 + sl;
        *(float4*)dst = make_float4(acc2[i][0].x, acc2[i][0].y, acc2[i][1].x, acc2[i][1].y);
    }
}

// ---------------------------------------------------------------------------
extern "C" void kernel_launch(void* const* d_in, const int* in_sizes, int n_in,
                              void* d_out, int out_size, void* d_ws, size_t ws_size,
                              hipStream_t stream)
{
    const float* x  = (const float*)d_in[0];
    const float* Wq = (const float*)d_in[1];
    const float* Wk = (const float*)d_in[2];
    const float* Wv = (const float*)d_in[3];
    const float* Wo = (const float*)d_in[4];
    const float* cw = (const float*)d_in[5];
    const float* cb = (const float*)d_in[6];
    float* Out = (float*)d_out;

    char* ws = (char*)d_ws;
    float* QC   = (float*)(ws);                               // 8 MB  Q channel-major [b][c][s], normalized
    float* KT   = (float*)(ws + (size_t)8  * 1024 * 1024);    // 8 MB  [b][s][c], normalized
    float* VT   = (float*)(ws + (size_t)16 * 1024 * 1024);    // 8 MB  [b][s][c], raw
    int*   IDXb = (int*)  (ws + (size_t)24 * 1024 * 1024);    // 1.2 MB [b][t][9]
    float* wT3  = (float*)(ws + (size_t)26 * 1024 * 1024);    // 147 KB
    float* out1 = QC;   // QC dead after sim_topk; reuse as conv output [b][t][o]

    gemm_qkv<<<dim3(32, 8, 3), dim3(512), 0, stream>>>(x, Wq, Wk, Wv, QC, KT, VT);
    sim_topk<<<dim3(1024), dim3(512), 0, stream>>>(QC, KT, IDXb);
    transpose_w<<<dim3(144), dim3(256), 0, stream>>>(cw, wT3);
    gather_conv<<<dim3(256, 8), dim3(256), 0, stream>>>(VT, IDXb, wT3, cb, out1);
    gemm_out<<<dim3(64, 8), dim3(256), 0, stream>>>(out1, Wo, Out);
}